// Round 1
// 88.739 us; speedup vs baseline: 1.0019x; 1.0019x over previous
//
#include <hip/hip_runtime.h>

#define NB 50
#define BLOCK 256

// out = relu(x@W1+b1) . V[id] + c[id]
//   V[id][k] = sum_j W2[k][j]*Wh[id][j]   (second layer folded into head)
//   c[id]    = sum_j b2[j]*Wh[id][j] + bh[id]
//
// V is stored fp16, TRANSPOSED-PAIR layout: half2 slot = k2*64 + id
// (k2 = k/2, stride padded to 64). For a ds_read_b32 at fixed k2, lane bank
// = id % 32 -> at most 2 distinct addresses per bank (id vs id+32), and
// 2-way LDS aliasing is free on gfx950. k2 offsets fold into the DS
// 16-bit immediate (k2*256 bytes), so address math is ~1 VALU per element.
//
// v2 change (occupancy A/B): 2 elements/thread instead of 4.
// Grid 1954 -> 3907 blocks, 7.6 -> 15.3 waves/SIMD. x load becomes one
// fully-coalesced float4/lane (was 2x stride-32B), buckets int2, out float2.
// Per-element VALU unchanged; tests whether lightwin was latency-bound.
//
// ws layout (uint32 units):
//   [   0,1024): VhT half2 bits, slot k2*64+id (ids 50..63 zero)
//   [1024,1088): c[id] float bits (50 valid)
//   [1088,1104): w0h2[k2] = (W1[0][2k2], W1[0][2k2+1]) as half2
//   [1104,1120): w1h2[k2]
//   [1120,1136): bh2[k2]  = (b1[2k2], b1[2k2+1])
// Main kernel stages [0,1088) into LDS; weight half2s are read uniformly
// from global ws (scalar loads).

typedef _Float16 hvec2 __attribute__((ext_vector_type(2)));

union h2bits { unsigned u; hvec2 h; };

__device__ __forceinline__ hvec2 u2h2(unsigned u) {
    h2bits c; c.u = u; return c.h;
}

__device__ __forceinline__ float dot2acc(hvec2 a, hvec2 b, float c) {
#if __has_builtin(__builtin_amdgcn_fdot2)
    return __builtin_amdgcn_fdot2(a, b, c, false);
#else
    return fmaf((float)a.x, (float)b.x, fmaf((float)a.y, (float)b.y, c));
#endif
}

__global__ __launch_bounds__(BLOCK) void precompute_kernel(
    const float* __restrict__ W1,   // [2][32]
    const float* __restrict__ b1,   // [32]
    const float* __restrict__ W2,   // [32][16]
    const float* __restrict__ b2,   // [16]
    const float* __restrict__ Wh,   // [50][16]
    const float* __restrict__ bh,   // [50]
    unsigned*    __restrict__ ws)
{
    int t = blockIdx.x * BLOCK + threadIdx.x;
    if (t < 1024) {
        int k2 = t >> 6;
        int id = t & 63;
        unsigned bits = 0u;
        if (id < NB) {
            float f0 = 0.f, f1 = 0.f;
            int k0 = 2 * k2, k1 = 2 * k2 + 1;
            #pragma unroll
            for (int j = 0; j < 16; ++j) {
                f0 = fmaf(W2[(k0 << 4) + j], Wh[(id << 4) + j], f0);
                f1 = fmaf(W2[(k1 << 4) + j], Wh[(id << 4) + j], f1);
            }
            h2bits c;
            c.h.x = (_Float16)f0;
            c.h.y = (_Float16)f1;
            bits = c.u;
        }
        ws[t] = bits;
    } else if (t < 1088) {
        int id = t - 1024;
        unsigned bits = 0u;
        if (id < NB) {
            float s = bh[id];
            #pragma unroll
            for (int j = 0; j < 16; ++j)
                s = fmaf(b2[j], Wh[(id << 4) + j], s);
            bits = __float_as_uint(s);
        }
        ws[t] = bits;
    } else if (t < 1136) {
        int i = t - 1088;
        int plane = i >> 4;         // 0:w0 1:w1 2:b
        int k2 = i & 15;
        float f0, f1;
        if (plane == 0)      { f0 = W1[2 * k2];      f1 = W1[2 * k2 + 1]; }
        else if (plane == 1) { f0 = W1[32 + 2 * k2]; f1 = W1[32 + 2 * k2 + 1]; }
        else                 { f0 = b1[2 * k2];      f1 = b1[2 * k2 + 1]; }
        h2bits c;
        c.h.x = (_Float16)f0;
        c.h.y = (_Float16)f1;
        ws[t] = c.u;
    }
}

__global__ __launch_bounds__(BLOCK) void lightwin_kernel(
    const float4*   __restrict__ xq,    // [B/2] — one float4 = 2 elements
    const int2*     __restrict__ bq,    // [B/2]
    const unsigned* __restrict__ wsu,
    float2*         __restrict__ outq,  // [B/2]
    int nq)
{
    __shared__ unsigned sU[1088];       // VhT [0,1024) + c bits [1024,1088)

    int tid = blockIdx.x * BLOCK + threadIdx.x;
    bool active = tid < nq;

    // Issue per-element global loads first to overlap LDS staging.
    float4 xa = {};
    int2 ib = {};
    if (active) {
        xa = xq[tid];
        ib = bq[tid];
    }

    // Coalesced staging: 1088 uints = 272 float4.
    {
        float4* sq = (float4*)sU;
        const float4* wq = (const float4*)wsu;
        for (int t = threadIdx.x; t < 272; t += BLOCK)
            sq[t] = wq[t];
    }
    __syncthreads();
    if (!active) return;

    int id0 = ib.x < NB ? ib.x : NB - 1;
    int id1 = ib.y < NB ? ib.y : NB - 1;

    float acc0 = __uint_as_float(sU[1024 + id0]);
    float acc1 = __uint_as_float(sU[1024 + id1]);

    // Broadcast x into packed halves.
    #define SPLAT2(f) (hvec2){(_Float16)(f), (_Float16)(f)}
    hvec2 x0e0 = SPLAT2(xa.x), x1e0 = SPLAT2(xa.y);
    hvec2 x0e1 = SPLAT2(xa.z), x1e1 = SPLAT2(xa.w);
    const hvec2 z2 = (hvec2)0;

    const unsigned* wp0 = wsu + 1088;   // uniform -> s_load
    const unsigned* wp1 = wsu + 1104;
    const unsigned* wpb = wsu + 1120;

    #pragma unroll
    for (int k2 = 0; k2 < 16; ++k2) {
        hvec2 w0 = u2h2(wp0[k2]);
        hvec2 w1 = u2h2(wp1[k2]);
        hvec2 bb = u2h2(wpb[k2]);
        // h2 = relu(x0*w0 + x1*w1 + b) in packed fp16 (contracts to v_pk_fma);
        // dot2 accumulate in f32.
        hvec2 h0 = __builtin_elementwise_max(x0e0 * w0 + x1e0 * w1 + bb, z2);
        hvec2 h1 = __builtin_elementwise_max(x0e1 * w0 + x1e1 * w1 + bb, z2);
        acc0 = dot2acc(h0, u2h2(sU[(k2 << 6) + id0]), acc0);
        acc1 = dot2acc(h1, u2h2(sU[(k2 << 6) + id1]), acc1);
    }

    float2 o; o.x = acc0; o.y = acc1;
    outq[tid] = o;
}

extern "C" void kernel_launch(void* const* d_in, const int* in_sizes, int n_in,
                              void* d_out, int out_size, void* d_ws, size_t ws_size,
                              hipStream_t stream) {
    const float* x       = (const float*)d_in[0];
    const int*   buckets = (const int*)d_in[1];
    const float* W1      = (const float*)d_in[2];
    const float* b1      = (const float*)d_in[3];
    const float* W2      = (const float*)d_in[4];
    const float* b2      = (const float*)d_in[5];
    const float* Wh      = (const float*)d_in[6];
    const float* bh      = (const float*)d_in[7];
    float* out = (float*)d_out;
    unsigned* ws = (unsigned*)d_ws;

    int B  = in_sizes[1];   // 2,000,000
    int nq = B / 2;

    precompute_kernel<<<(1136 + BLOCK - 1) / BLOCK, BLOCK, 0, stream>>>(
        W1, b1, W2, b2, Wh, bh, ws);

    int grid = (nq + BLOCK - 1) / BLOCK;
    lightwin_kernel<<<grid, BLOCK, 0, stream>>>(
        (const float4*)x, (const int2*)buckets, ws, (float2*)out, nq);
}